// Round 8
// baseline (260.981 us; speedup 1.0000x reference)
//
#include <hip/hip_runtime.h>

#define TB_L 1024
#define TB_E 1024

typedef __attribute__((ext_vector_type(8))) short bf16x8;
typedef __attribute__((ext_vector_type(8))) unsigned short u16x8;
typedef __attribute__((ext_vector_type(4))) float floatx4;

#define AS1(p) ((const __attribute__((address_space(1))) void*)(p))
#define AS3(p) ((__attribute__((address_space(3))) void*)(p))

static __device__ __forceinline__ unsigned short f2bf(float x) {
  union { float f; unsigned u; } c; c.f = x;
  unsigned r = c.u + 0x7fff + ((c.u >> 16) & 1);
  return (unsigned short)(r >> 16);
}
static __device__ __forceinline__ float gelu_f(float x) {
  const float c0 = 0.7978845608028654f;
  const float c1 = 0.044715f;
  float x3 = x * x * x;
  return 0.5f * x * (1.0f + tanhf(c0 * (x + c1 * x3)));
}

// swizzled LDS addressing for 64-row x 128-byte tiles: 16B chunk XOR row&7
static __device__ __forceinline__ int swz(int row, int bytecol) {
  return row * 128 + ((((bytecol >> 4) ^ (row & 7)) << 4) | (bytecol & 15));
}

// RMS norm over E=1024, one block per row, bf16 output.
__global__ __launch_bounds__(256) void rms_kernel(const float* __restrict__ x,
                                                  const float* __restrict__ w,
                                                  unsigned short* __restrict__ out) {
  const int row = blockIdx.x;
  const int tid = threadIdx.x;
  const float4 v = *(const float4*)(x + (size_t)row * TB_E + tid * 4);
  float s = v.x * v.x + v.y * v.y + v.z * v.z + v.w * v.w;
#pragma unroll
  for (int off = 32; off > 0; off >>= 1) s += __shfl_down(s, off);
  __shared__ float red[4];
  if ((tid & 63) == 0) red[tid >> 6] = s;
  __syncthreads();
  const float tot = red[0] + red[1] + red[2] + red[3];
  const float scale = rsqrtf(tot * (1.0f / TB_E) + 1e-6f);
  const float4 wv = *(const float4*)(w + tid * 4);
  ushort4 o;
  o.x = f2bf(v.x * scale * wv.x);
  o.y = f2bf(v.y * scale * wv.y);
  o.z = f2bf(v.z * scale * wv.z);
  o.w = f2bf(v.w * scale * wv.w);
  *(ushort4*)(out + (size_t)row * TB_E + tid * 4) = o;
}

// Fused transpose+bf16 of all 4 weights: in K x N fp32 -> out N x K bf16.
__global__ __launch_bounds__(256) void transpose_all(
    const float* __restrict__ s0, const float* __restrict__ s1,
    const float* __restrict__ s2, const float* __restrict__ s3,
    unsigned short* __restrict__ d0, unsigned short* __restrict__ d1,
    unsigned short* __restrict__ d2, unsigned short* __restrict__ d3) {
  const int id = blockIdx.x;
  const float* in; unsigned short* out; int K, N, lid;
  if (id < 768)       { in = s0; out = d0; K = 1024; N = 3072; lid = id; }
  else if (id < 1024) { in = s1; out = d1; K = 1024; N = 1024; lid = id - 768; }
  else if (id < 2048) { in = s2; out = d2; K = 1024; N = 4096; lid = id - 1024; }
  else                { in = s3; out = d3; K = 4096; N = 1024; lid = id - 2048; }
  const int nx = N >> 6;
  const int n0 = (lid % nx) * 64, k0 = (lid / nx) * 64;
  __shared__ float t[64][65];
  const int tid = threadIdx.x;
#pragma unroll
  for (int rep = 0; rep < 4; ++rep) {
    const int r = rep * 16 + (tid >> 4);
    const int c = (tid & 15) * 4;
    const float4 v = *(const float4*)(in + (size_t)(k0 + r) * N + n0 + c);
    t[r][c] = v.x; t[r][c + 1] = v.y; t[r][c + 2] = v.z; t[r][c + 3] = v.w;
  }
  __syncthreads();
#pragma unroll
  for (int rep = 0; rep < 4; ++rep) {
    const int n = rep * 16 + (tid >> 4);
    const int k = (tid & 15) * 4;
    ushort4 o;
    o.x = f2bf(t[k + 0][n]);
    o.y = f2bf(t[k + 1][n]);
    o.z = f2bf(t[k + 2][n]);
    o.w = f2bf(t[k + 3][n]);
    *(ushort4*)(out + (size_t)(n0 + n) * K + k0 + k) = o;
  }
}

// bf16 MFMA GEMM, double-buffered LDS.
// A: M x K bf16 row-major.  Bt: N x K bf16 (k-contiguous).
// relu_ncut: cols n < relu_ncut get relu (post-bias) -- used for q,k.
// VT: also scatter v-columns (n>=2048) transposed into vtp[bh][d][l] (qkv only).
// Cpart: raw fp32 partial to Cpart + blockIdx.z*M*N (split-K).
template <int BM, int BN, int BK, int WM, int WN, int NTH, bool GELU, bool VT>
__global__ __launch_bounds__(NTH) void gemm_bf16(
    const unsigned short* __restrict__ A, const unsigned short* __restrict__ Bt,
    const float* __restrict__ bias, const float* __restrict__ res,
    float* __restrict__ Cf, unsigned short* __restrict__ Cb,
    float* __restrict__ Cpart, unsigned short* __restrict__ vtp,
    int relu_ncut, int M, int N, int K, int Ksl) {
  constexpr int NW = NTH / 64;
  constexpr int KC = BK / 32;
  constexpr int WCOLS = BN / WN;
  constexpr int MT = WM / 16;
  constexpr int NT = WN / 16;
  constexpr int ACH = (BM / 16) * KC;
  constexpr int BCH = (BN / 16) * KC;
  static_assert((BM / WM) * (BN / WN) == NW, "wave grid");
  static_assert(ACH % NW == 0 && BCH % NW == 0, "chunks divisible by waves");
  __shared__ __align__(16) unsigned short As[2][BM * BK];
  __shared__ __align__(16) unsigned short Bs[2][BN * BK];
  const int tid = threadIdx.x;
  const int wid = tid >> 6, lane = tid & 63;

  constexpr int G = 4;
  const int nbx = gridDim.x;
  const int flat = blockIdx.y * nbx + blockIdx.x;
  const int grp = flat / (G * nbx), rem = flat % (G * nbx);
  const int m0 = (grp * G + rem % G) * BM;
  const int n0 = (rem / G) * BN;

  const int k_off = blockIdx.z * Ksl;
  const int mbase = (wid / WCOLS) * WM, nbase = (wid % WCOLS) * WN;

  floatx4 acc[MT][NT];
#pragma unroll
  for (int i = 0; i < MT; ++i)
#pragma unroll
    for (int j = 0; j < NT; ++j) {
      floatx4 z = {0.f, 0.f, 0.f, 0.f};
      acc[i][j] = z;
    }

  const int srow = lane >> 2;
  const int scol = (lane & 3) * 8;
  const unsigned short* Ag = A + (size_t)m0 * K + k_off;
  const unsigned short* Bg = Bt + (size_t)n0 * K + k_off;
  const int fr = (lane & 15);
  const int fk = (lane >> 4) * 16;

  auto stage = [&](int buf, int k0) {
#pragma unroll
    for (int j = 0; j < ACH / NW; ++j) {
      const int ch = j * NW + wid;
      const int strip = ch / KC, half = ch % KC;
      __builtin_amdgcn_global_load_lds(
          AS1(Ag + (size_t)(strip * 16 + srow) * K + k0 + half * 32 + scol),
          AS3((char*)&As[buf][0] + ch * 1024), 16, 0, 0);
    }
#pragma unroll
    for (int j = 0; j < BCH / NW; ++j) {
      const int ch = j * NW + wid;
      const int strip = ch / KC, half = ch % KC;
      __builtin_amdgcn_global_load_lds(
          AS1(Bg + (size_t)(strip * 16 + srow) * K + k0 + half * 32 + scol),
          AS3((char*)&Bs[buf][0] + ch * 1024), 16, 0, 0);
    }
  };

  stage(0, 0);
  const int nsteps = Ksl / BK;
  for (int s = 0; s < nsteps; ++s) {
    __syncthreads();
    const int cur = s & 1;
    if (s + 1 < nsteps) stage(cur ^ 1, (s + 1) * BK);
    const char* Ab = (const char*)&As[cur][0];
    const char* Bb = (const char*)&Bs[cur][0];
#pragma unroll
    for (int g = 0; g < KC; ++g) {
      bf16x8 af[MT], bfr[NT];
#pragma unroll
      for (int i = 0; i < MT; ++i)
        af[i] = *(const bf16x8*)(Ab + ((mbase / 16 + i) * KC + g) * 1024 +
                                 fr * 64 + fk);
#pragma unroll
      for (int j = 0; j < NT; ++j)
        bfr[j] = *(const bf16x8*)(Bb + ((nbase / 16 + j) * KC + g) * 1024 +
                                  fr * 64 + fk);
#pragma unroll
      for (int i = 0; i < MT; ++i)
#pragma unroll
        for (int j = 0; j < NT; ++j)
          acc[i][j] = __builtin_amdgcn_mfma_f32_16x16x32_bf16(af[i], bfr[j],
                                                              acc[i][j], 0, 0, 0);
    }
  }

  const int mr = (lane >> 4) * 4;
  const int nc = lane & 15;
  float* P = Cpart ? (Cpart + (size_t)blockIdx.z * M * N) : nullptr;
#pragma unroll
  for (int i = 0; i < MT; ++i)
#pragma unroll
    for (int j = 0; j < NT; ++j) {
      const int n = n0 + nbase + j * 16 + nc;
      const float bv = bias ? bias[n] : 0.f;
      float tv[4];
#pragma unroll
      for (int r = 0; r < 4; ++r) {
        const int m = m0 + mbase + i * 16 + mr + r;
        float v = acc[i][j][r] + bv;
        if (GELU) v = gelu_f(v);
        if (n < relu_ncut) v = fmaxf(v, 0.f);
        if (res) v += res[(size_t)m * N + n];
        if (P) P[(size_t)m * N + n] = v;
        if (Cf) Cf[(size_t)m * N + n] = v;
        if (Cb) Cb[(size_t)m * N + n] = f2bf(v);
        tv[r] = v;
      }
      if (VT && n >= 2048) {
        const int mm = m0 + mbase + i * 16 + mr;
        const int bb = mm >> 10, l = mm & 1023;
        const int hh = (n - 2048) >> 6, dd = (n - 2048) & 63;
        ushort4 o;
        o.x = f2bf(tv[0]); o.y = f2bf(tv[1]);
        o.z = f2bf(tv[2]); o.w = f2bf(tv[3]);
        *(ushort4*)(vtp + (size_t)(bb * 16 + hh) * 65536 + dd * 1024 + l) = o;
      }
    }
}

// out = sum_{z<4} P_z + b2[n] + h, N=1024, M=2048 (split-K reduce + epilogue)
__global__ __launch_bounds__(256) void reduce_out(const float* __restrict__ P,
                                                  const float* __restrict__ h,
                                                  const float* __restrict__ b2,
                                                  float* __restrict__ out) {
  const int idx = (blockIdx.x * 256 + threadIdx.x) * 4;
  const int n = idx & 1023;
  const float4 a0 = *(const float4*)(P + idx);
  const float4 a1 = *(const float4*)(P + 2097152 + idx);
  const float4 a2 = *(const float4*)(P + 2 * 2097152 + idx);
  const float4 a3 = *(const float4*)(P + 3 * 2097152 + idx);
  const float4 hh = *(const float4*)(h + idx);
  const float4 bb = *(const float4*)(b2 + n);
  float4 o;
  o.x = a0.x + a1.x + a2.x + a3.x + hh.x + bb.x;
  o.y = a0.y + a1.y + a2.y + a3.y + hh.y + bb.y;
  o.z = a0.z + a1.z + a2.z + a3.z + hh.z + bb.z;
  o.w = a0.w + a1.w + a2.w + a3.w + hh.w + bb.w;
  *(float4*)(out + idx) = o;
}

// Cosformer causal linear attention, MFMA flash-style, async-staged.
// qkv holds relu'd q,k (done in qkv-GEMM epilogue); vt = V^T [bh][d][l].
__global__ __launch_bounds__(256) void attn_mfma(
    const unsigned short* __restrict__ qkv,
    const unsigned short* __restrict__ vt,
    unsigned short* __restrict__ out) {
  const int bh = blockIdx.x;
  const int it = blockIdx.y;
  const int b = bh >> 4, h = bh & 15;
  const int tid = threadIdx.x;
  const int w = tid >> 6, lane = tid & 63;
  const int qd = lane >> 4, ln = lane & 15;
  const int i0 = it * 64;
  __shared__ __align__(16) char sq[8192];
  __shared__ __align__(16) char sk[2][8192];
  __shared__ __align__(16) char sv[2][8192];
  __shared__ __align__(16) char ss[8192];
  const unsigned short* qbase = qkv + (size_t)b * (TB_L * 3072) + h * 64;
  const unsigned short* kbase = qbase + 1024;
  const unsigned short* vbase = vt + (size_t)bh * 65536;
  const float PH = 1.5339807878856412e-3f;  // pi/2/1024

  const int sr = lane >> 3;
  const int cg = ((lane & 7) ^ sr) * 8;

#pragma unroll
  for (int p = 0; p < 2; ++p) {
    const int ch = p * 4 + w;
    __builtin_amdgcn_global_load_lds(
        AS1(qbase + (size_t)(i0 + ch * 8 + sr) * 3072 + cg),
        AS3(sq + ch * 1024), 16, 0, 0);
  }
  auto stage_kv = [&](int buf, int jt) {
    const int j0 = jt * 64;
#pragma unroll
    for (int p = 0; p < 4; ++p) {
      const int ch = p * 4 + w;
      if (ch < 8) {
        __builtin_amdgcn_global_load_lds(
            AS1(kbase + (size_t)(j0 + ch * 8 + sr) * 3072 + cg),
            AS3(sk[buf] + ch * 1024), 16, 0, 0);
      } else {
        __builtin_amdgcn_global_load_lds(
            AS1(vbase + (size_t)((ch - 8) * 8 + sr) * 1024 + j0 + cg),
            AS3(sv[buf] + (ch - 8) * 1024), 16, 0, 0);
      }
    }
  };
  stage_kv(0, 0);
  __syncthreads();

  bf16x8 aq[2];
#pragma unroll
  for (int ks = 0; ks < 2; ++ks)
    aq[ks] = *(const bf16x8*)(sq + swz(w * 16 + ln, ks * 64 + qd * 16));

  float ci[4], si[4];
#pragma unroll
  for (int r = 0; r < 4; ++r)
    __sincosf(PH * (float)(i0 + w * 16 + qd * 4 + r), &si[r], &ci[r]);

  floatx4 acc_o[4], acc_n;
  {
    floatx4 z = {0.f, 0.f, 0.f, 0.f};
#pragma unroll
    for (int nt = 0; nt < 4; ++nt) acc_o[nt] = z;
    acc_n = z;
  }
  bf16x8 ones;
#pragma unroll
  for (int z = 0; z < 8; ++z) ones[z] = (short)0x3F80;

  for (int jt = 0; jt <= it; ++jt) {
    const int cur = jt & 1;
    if (jt < it) stage_kv(cur ^ 1, jt + 1);
    const char* skb = sk[cur];
    const char* svb = sv[cur];
    const int j0 = jt * 64;

    floatx4 s_acc[4];
    {
      floatx4 z = {0.f, 0.f, 0.f, 0.f};
#pragma unroll
      for (int nt = 0; nt < 4; ++nt) s_acc[nt] = z;
    }
#pragma unroll
    for (int ks = 0; ks < 2; ++ks)
#pragma unroll
      for (int nt = 0; nt < 4; ++nt) {
        const bf16x8 bk =
            *(const bf16x8*)(skb + swz(nt * 16 + ln, ks * 64 + qd * 16));
        s_acc[nt] =
            __builtin_amdgcn_mfma_f32_16x16x32_bf16(aq[ks], bk, s_acc[nt], 0, 0, 0);
      }

    float cj[4], sj[4];
#pragma unroll
    for (int nt = 0; nt < 4; ++nt)
      __sincosf(PH * (float)(j0 + nt * 16 + ln), &sj[nt], &cj[nt]);
    const bool diag = (jt == it);
    const int li = w * 16 + qd * 4;
#pragma unroll
    for (int nt = 0; nt < 4; ++nt) {
      const int jl = nt * 16 + ln;
#pragma unroll
      for (int r = 0; r < 4; ++r) {
        float val = s_acc[nt][r] * (ci[r] * cj[nt] + si[r] * sj[nt]);
        if (diag && jl > li + r) val = 0.f;
        *(unsigned short*)(ss + swz(li + r, jl * 2)) = f2bf(val);
      }
    }

#pragma unroll
    for (int ks = 0; ks < 2; ++ks) {
      const bf16x8 as = *(const bf16x8*)(ss + swz(w * 16 + ln, ks * 64 + qd * 16));
#pragma unroll
      for (int nt = 0; nt < 4; ++nt) {
        const bf16x8 bv =
            *(const bf16x8*)(svb + swz(nt * 16 + ln, ks * 64 + qd * 16));
        acc_o[nt] =
            __builtin_amdgcn_mfma_f32_16x16x32_bf16(as, bv, acc_o[nt], 0, 0, 0);
      }
      acc_n = __builtin_amdgcn_mfma_f32_16x16x32_bf16(as, ones, acc_n, 0, 0, 0);
    }
    __syncthreads();
  }

#pragma unroll
  for (int r = 0; r < 4; ++r) {
    const float inv = 1.0f / (acc_n[r] + 1e-6f);
    unsigned short* op =
        out + (size_t)(b * TB_L + i0 + w * 16 + qd * 4 + r) * TB_E + h * 64;
#pragma unroll
    for (int nt = 0; nt < 4; ++nt) op[nt * 16 + ln] = f2bf(acc_o[nt][r] * inv);
  }
}

extern "C" void kernel_launch(void* const* d_in, const int* in_sizes, int n_in,
                              void* d_out, int out_size, void* d_ws, size_t ws_size,
                              hipStream_t stream) {
  const float* x     = (const float*)d_in[0];
  const float* qkv_w = (const float*)d_in[1];
  const float* qkv_b = (const float*)d_in[2];
  const float* out_w = (const float*)d_in[3];
  const float* out_b = (const float*)d_in[4];
  const float* n1w   = (const float*)d_in[5];
  const float* n2w   = (const float*)d_in[6];
  const float* w1    = (const float*)d_in[7];
  const float* b1    = (const float*)d_in[8];
  const float* w2    = (const float*)d_in[9];
  const float* b2    = (const float*)d_in[10];

  char* wsb = (char*)d_ws;
  unsigned short* qkvb  = (unsigned short*)wsb;              // 2048x3072 bf16
  unsigned short* g     = (unsigned short*)wsb;              // later: 2048x4096 bf16
  unsigned short* vt    = (unsigned short*)(wsb + 12582912); // 32x64x1024 bf16 (4MB)
  unsigned short* xnb   = (unsigned short*)(wsb + 16777216);
  unsigned short* attnb = (unsigned short*)(wsb + 20971520);
  float*          h     = (float*)(wsb + 25165824);
  unsigned short* qkvwt = (unsigned short*)(wsb + 33554432);
  unsigned short* outwt = (unsigned short*)(wsb + 39845888);
  unsigned short* w1t   = (unsigned short*)(wsb + 41943040);
  unsigned short* w2t   = (unsigned short*)(wsb + 50331648);
  float*          Pk    = (float*)(wsb + 67108864);  // 4 x 8.4MB fp32 partials
  float* out = (float*)d_out;
  const int M = 2048;

  transpose_all<<<dim3(3072), 256, 0, stream>>>(qkv_w, out_w, w1, w2,
                                                qkvwt, outwt, w1t, w2t);

  rms_kernel<<<dim3(M), 256, 0, stream>>>(x, n1w, xnb);
  // qkv: 128x128 m97-shape; relu'd q,k; v also transposed into vt
  gemm_bf16<128, 128, 64, 64, 64, 256, false, true><<<dim3(24, 16), 256, 0, stream>>>(
      xnb, qkvwt, qkv_b, nullptr, nullptr, qkvb, nullptr, vt, 2048, M, 3072, 1024, 1024);
  attn_mfma<<<dim3(32, 16), 256, 0, stream>>>(qkvb, vt, attnb);
  gemm_bf16<64, 64, 64, 32, 32, 256, false, false><<<dim3(16, 32), 256, 0, stream>>>(
      attnb, outwt, out_b, x, h, nullptr, nullptr, nullptr, 0, M, 1024, 1024, 1024);
  rms_kernel<<<dim3(M), 256, 0, stream>>>(h, n2w, xnb);
  gemm_bf16<128, 128, 64, 64, 64, 256, true, false><<<dim3(32, 16), 256, 0, stream>>>(
      xnb, w1t, b1, nullptr, nullptr, g, nullptr, nullptr, 0, M, 4096, 1024, 1024);
  gemm_bf16<128, 128, 64, 64, 64, 256, false, false><<<dim3(8, 16, 4), 256, 0, stream>>>(
      g, w2t, nullptr, nullptr, nullptr, nullptr, Pk, nullptr, 0, M, 1024, 4096, 1024);
  reduce_out<<<dim3(2048), 256, 0, stream>>>(Pk, h, b2, out);
}

// Round 9
// 245.195 us; speedup vs baseline: 1.0644x; 1.0644x over previous
//
#include <hip/hip_runtime.h>

#define TB_L 1024
#define TB_E 1024

typedef __attribute__((ext_vector_type(8))) short bf16x8;
typedef __attribute__((ext_vector_type(8))) unsigned short u16x8;
typedef __attribute__((ext_vector_type(4))) float floatx4;

#define AS1(p) ((const __attribute__((address_space(1))) void*)(p))
#define AS3(p) ((__attribute__((address_space(3))) void*)(p))

static __device__ __forceinline__ unsigned short f2bf(float x) {
  union { float f; unsigned u; } c; c.f = x;
  unsigned r = c.u + 0x7fff + ((c.u >> 16) & 1);
  return (unsigned short)(r >> 16);
}
// tanh-approx gelu via hw exp2: gelu = x * t/(t+1), t = e^{2y}, y = c0(x+c1 x^3)
// (t/(t+1) = (1+tanh y)/2 exactly). ~8 VALU ops vs ~40 for libm tanhf.
static __device__ __forceinline__ float gelu_f(float x) {
  const float c0 = 0.7978845608028654f;
  const float c1 = 0.044715f;
  float y = c0 * x * fmaf(c1, x * x, 1.0f);
  y = fminf(fmaxf(y, -15.f), 15.f);
  const float t = __builtin_amdgcn_exp2f(2.8853900817779268f * y);
  return x * t * __builtin_amdgcn_rcpf(t + 1.0f);
}

// swizzled LDS addressing for 64-row x 128-byte tiles: 16B chunk XOR row&7
static __device__ __forceinline__ int swz(int row, int bytecol) {
  return row * 128 + ((((bytecol >> 4) ^ (row & 7)) << 4) | (bytecol & 15));
}

// RMS norm over E=1024, one block per row, bf16 output.
__global__ __launch_bounds__(256) void rms_kernel(const float* __restrict__ x,
                                                  const float* __restrict__ w,
                                                  unsigned short* __restrict__ out) {
  const int row = blockIdx.x;
  const int tid = threadIdx.x;
  const float4 v = *(const float4*)(x + (size_t)row * TB_E + tid * 4);
  float s = v.x * v.x + v.y * v.y + v.z * v.z + v.w * v.w;
#pragma unroll
  for (int off = 32; off > 0; off >>= 1) s += __shfl_down(s, off);
  __shared__ float red[4];
  if ((tid & 63) == 0) red[tid >> 6] = s;
  __syncthreads();
  const float tot = red[0] + red[1] + red[2] + red[3];
  const float scale = rsqrtf(tot * (1.0f / TB_E) + 1e-6f);
  const float4 wv = *(const float4*)(w + tid * 4);
  ushort4 o;
  o.x = f2bf(v.x * scale * wv.x);
  o.y = f2bf(v.y * scale * wv.y);
  o.z = f2bf(v.z * scale * wv.z);
  o.w = f2bf(v.w * scale * wv.w);
  *(ushort4*)(out + (size_t)row * TB_E + tid * 4) = o;
}

// Fused transpose+bf16 of all 4 weights: in K x N fp32 -> out N x K bf16.
__global__ __launch_bounds__(256) void transpose_all(
    const float* __restrict__ s0, const float* __restrict__ s1,
    const float* __restrict__ s2, const float* __restrict__ s3,
    unsigned short* __restrict__ d0, unsigned short* __restrict__ d1,
    unsigned short* __restrict__ d2, unsigned short* __restrict__ d3) {
  const int id = blockIdx.x;
  const float* in; unsigned short* out; int K, N, lid;
  if (id < 768)       { in = s0; out = d0; K = 1024; N = 3072; lid = id; }
  else if (id < 1024) { in = s1; out = d1; K = 1024; N = 1024; lid = id - 768; }
  else if (id < 2048) { in = s2; out = d2; K = 1024; N = 4096; lid = id - 1024; }
  else                { in = s3; out = d3; K = 4096; N = 1024; lid = id - 2048; }
  const int nx = N >> 6;
  const int n0 = (lid % nx) * 64, k0 = (lid / nx) * 64;
  __shared__ float t[64][65];
  const int tid = threadIdx.x;
#pragma unroll
  for (int rep = 0; rep < 4; ++rep) {
    const int r = rep * 16 + (tid >> 4);
    const int c = (tid & 15) * 4;
    const float4 v = *(const float4*)(in + (size_t)(k0 + r) * N + n0 + c);
    t[r][c] = v.x; t[r][c + 1] = v.y; t[r][c + 2] = v.z; t[r][c + 3] = v.w;
  }
  __syncthreads();
#pragma unroll
  for (int rep = 0; rep < 4; ++rep) {
    const int n = rep * 16 + (tid >> 4);
    const int k = (tid & 15) * 4;
    ushort4 o;
    o.x = f2bf(t[k + 0][n]);
    o.y = f2bf(t[k + 1][n]);
    o.z = f2bf(t[k + 2][n]);
    o.w = f2bf(t[k + 3][n]);
    *(ushort4*)(out + (size_t)(n0 + n) * K + k0 + k) = o;
  }
}

// bf16 MFMA GEMM, double-buffered LDS.
// A: M x K bf16 row-major.  Bt: N x K bf16 (k-contiguous).
// relu_ncut: cols n < relu_ncut get relu (post-bias) -- used for q,k.
// VT: also scatter v-columns (n>=2048) transposed into vtp[bh][d][l] (qkv only).
// Cpart: raw fp32 partial to Cpart + blockIdx.z*M*N (split-K).
template <int BM, int BN, int BK, int WM, int WN, int NTH, bool GELU, bool VT>
__global__ __launch_bounds__(NTH) void gemm_bf16(
    const unsigned short* __restrict__ A, const unsigned short* __restrict__ Bt,
    const float* __restrict__ bias, const float* __restrict__ res,
    float* __restrict__ Cf, unsigned short* __restrict__ Cb,
    float* __restrict__ Cpart, unsigned short* __restrict__ vtp,
    int relu_ncut, int M, int N, int K, int Ksl) {
  constexpr int NW = NTH / 64;
  constexpr int KC = BK / 32;
  constexpr int WCOLS = BN / WN;
  constexpr int MT = WM / 16;
  constexpr int NT = WN / 16;
  constexpr int ACH = (BM / 16) * KC;
  constexpr int BCH = (BN / 16) * KC;
  static_assert((BM / WM) * (BN / WN) == NW, "wave grid");
  static_assert(ACH % NW == 0 && BCH % NW == 0, "chunks divisible by waves");
  __shared__ __align__(16) unsigned short As[2][BM * BK];
  __shared__ __align__(16) unsigned short Bs[2][BN * BK];
  const int tid = threadIdx.x;
  const int wid = tid >> 6, lane = tid & 63;

  constexpr int G = 4;
  const int nbx = gridDim.x;
  const int flat = blockIdx.y * nbx + blockIdx.x;
  const int grp = flat / (G * nbx), rem = flat % (G * nbx);
  const int m0 = (grp * G + rem % G) * BM;
  const int n0 = (rem / G) * BN;

  const int k_off = blockIdx.z * Ksl;
  const int mbase = (wid / WCOLS) * WM, nbase = (wid % WCOLS) * WN;

  floatx4 acc[MT][NT];
#pragma unroll
  for (int i = 0; i < MT; ++i)
#pragma unroll
    for (int j = 0; j < NT; ++j) {
      floatx4 z = {0.f, 0.f, 0.f, 0.f};
      acc[i][j] = z;
    }

  const int srow = lane >> 2;
  const int scol = (lane & 3) * 8;
  const unsigned short* Ag = A + (size_t)m0 * K + k_off;
  const unsigned short* Bg = Bt + (size_t)n0 * K + k_off;
  const int fr = (lane & 15);
  const int fk = (lane >> 4) * 16;

  auto stage = [&](int buf, int k0) {
#pragma unroll
    for (int j = 0; j < ACH / NW; ++j) {
      const int ch = j * NW + wid;
      const int strip = ch / KC, half = ch % KC;
      __builtin_amdgcn_global_load_lds(
          AS1(Ag + (size_t)(strip * 16 + srow) * K + k0 + half * 32 + scol),
          AS3((char*)&As[buf][0] + ch * 1024), 16, 0, 0);
    }
#pragma unroll
    for (int j = 0; j < BCH / NW; ++j) {
      const int ch = j * NW + wid;
      const int strip = ch / KC, half = ch % KC;
      __builtin_amdgcn_global_load_lds(
          AS1(Bg + (size_t)(strip * 16 + srow) * K + k0 + half * 32 + scol),
          AS3((char*)&Bs[buf][0] + ch * 1024), 16, 0, 0);
    }
  };

  stage(0, 0);
  const int nsteps = Ksl / BK;
  for (int s = 0; s < nsteps; ++s) {
    __syncthreads();
    const int cur = s & 1;
    if (s + 1 < nsteps) stage(cur ^ 1, (s + 1) * BK);
    const char* Ab = (const char*)&As[cur][0];
    const char* Bb = (const char*)&Bs[cur][0];
#pragma unroll
    for (int g = 0; g < KC; ++g) {
      bf16x8 af[MT], bfr[NT];
#pragma unroll
      for (int i = 0; i < MT; ++i)
        af[i] = *(const bf16x8*)(Ab + ((mbase / 16 + i) * KC + g) * 1024 +
                                 fr * 64 + fk);
#pragma unroll
      for (int j = 0; j < NT; ++j)
        bfr[j] = *(const bf16x8*)(Bb + ((nbase / 16 + j) * KC + g) * 1024 +
                                  fr * 64 + fk);
#pragma unroll
      for (int i = 0; i < MT; ++i)
#pragma unroll
        for (int j = 0; j < NT; ++j)
          acc[i][j] = __builtin_amdgcn_mfma_f32_16x16x32_bf16(af[i], bfr[j],
                                                              acc[i][j], 0, 0, 0);
    }
  }

  const int mr = (lane >> 4) * 4;
  const int nc = lane & 15;
  float* P = Cpart ? (Cpart + (size_t)blockIdx.z * M * N) : nullptr;
#pragma unroll
  for (int i = 0; i < MT; ++i)
#pragma unroll
    for (int j = 0; j < NT; ++j) {
      const int n = n0 + nbase + j * 16 + nc;
      const float bv = bias ? bias[n] : 0.f;
      float tv[4];
#pragma unroll
      for (int r = 0; r < 4; ++r) {
        const int m = m0 + mbase + i * 16 + mr + r;
        float v = acc[i][j][r] + bv;
        if (GELU) v = gelu_f(v);
        if (n < relu_ncut) v = fmaxf(v, 0.f);
        if (res) v += res[(size_t)m * N + n];
        if (P) P[(size_t)m * N + n] = v;
        if (Cf) Cf[(size_t)m * N + n] = v;
        if (Cb) Cb[(size_t)m * N + n] = f2bf(v);
        tv[r] = v;
      }
      if (VT && n >= 2048) {
        const int mm = m0 + mbase + i * 16 + mr;
        const int bb = mm >> 10, l = mm & 1023;
        const int hh = (n - 2048) >> 6, dd = (n - 2048) & 63;
        ushort4 o;
        o.x = f2bf(tv[0]); o.y = f2bf(tv[1]);
        o.z = f2bf(tv[2]); o.w = f2bf(tv[3]);
        *(ushort4*)(vtp + (size_t)(bb * 16 + hh) * 65536 + dd * 1024 + l) = o;
      }
    }
}

// out = P0 + P1 + b2[n] + h, N=1024, M=2048 (split-K reduce + epilogue)
__global__ __launch_bounds__(256) void reduce_out(const float* __restrict__ P,
                                                  const float* __restrict__ h,
                                                  const float* __restrict__ b2,
                                                  float* __restrict__ out) {
  const int idx = (blockIdx.x * 256 + threadIdx.x) * 4;
  const int n = idx & 1023;
  const float4 a = *(const float4*)(P + idx);
  const float4 b = *(const float4*)(P + 2097152 + idx);
  const float4 hh = *(const float4*)(h + idx);
  const float4 bb = *(const float4*)(b2 + n);
  float4 o;
  o.x = a.x + b.x + hh.x + bb.x;
  o.y = a.y + b.y + hh.y + bb.y;
  o.z = a.z + b.z + hh.z + bb.z;
  o.w = a.w + b.w + hh.w + bb.w;
  *(float4*)(out + idx) = o;
}

// Cosformer causal linear attention, MFMA flash-style, async-staged.
// qkv holds relu'd q,k (done in qkv-GEMM epilogue); vt = V^T [bh][d][l].
// Grid (bh, y) with it = permute(y) so co-resident blocks balance the
// triangular work (pairs sum to 17 iterations).
__global__ __launch_bounds__(256) void attn_mfma(
    const unsigned short* __restrict__ qkv,
    const unsigned short* __restrict__ vt,
    unsigned short* __restrict__ out) {
  const int bh = blockIdx.x;
  const int y = blockIdx.y;
  const int it = (y < 8) ? (2 * y) : (31 - 2 * y);
  const int b = bh >> 4, h = bh & 15;
  const int tid = threadIdx.x;
  const int w = tid >> 6, lane = tid & 63;
  const int qd = lane >> 4, ln = lane & 15;
  const int i0 = it * 64;
  __shared__ __align__(16) char sq[8192];
  __shared__ __align__(16) char sk[2][8192];
  __shared__ __align__(16) char sv[2][8192];
  __shared__ __align__(16) char ss[8192];
  const unsigned short* qbase = qkv + (size_t)b * (TB_L * 3072) + h * 64;
  const unsigned short* kbase = qbase + 1024;
  const unsigned short* vbase = vt + (size_t)bh * 65536;
  const float PH = 1.5339807878856412e-3f;  // pi/2/1024

  const int sr = lane >> 3;
  const int cg = ((lane & 7) ^ sr) * 8;

#pragma unroll
  for (int p = 0; p < 2; ++p) {
    const int ch = p * 4 + w;
    __builtin_amdgcn_global_load_lds(
        AS1(qbase + (size_t)(i0 + ch * 8 + sr) * 3072 + cg),
        AS3(sq + ch * 1024), 16, 0, 0);
  }
  auto stage_kv = [&](int buf, int jt) {
    const int j0 = jt * 64;
#pragma unroll
    for (int p = 0; p < 4; ++p) {
      const int ch = p * 4 + w;
      if (ch < 8) {
        __builtin_amdgcn_global_load_lds(
            AS1(kbase + (size_t)(j0 + ch * 8 + sr) * 3072 + cg),
            AS3(sk[buf] + ch * 1024), 16, 0, 0);
      } else {
        __builtin_amdgcn_global_load_lds(
            AS1(vbase + (size_t)((ch - 8) * 8 + sr) * 1024 + j0 + cg),
            AS3(sv[buf] + (ch - 8) * 1024), 16, 0, 0);
      }
    }
  };
  stage_kv(0, 0);
  __syncthreads();

  bf16x8 aq[2];
#pragma unroll
  for (int ks = 0; ks < 2; ++ks)
    aq[ks] = *(const bf16x8*)(sq + swz(w * 16 + ln, ks * 64 + qd * 16));

  float ci[4], si[4];
#pragma unroll
  for (int r = 0; r < 4; ++r)
    __sincosf(PH * (float)(i0 + w * 16 + qd * 4 + r), &si[r], &ci[r]);

  floatx4 acc_o[4], acc_n;
  {
    floatx4 z = {0.f, 0.f, 0.f, 0.f};
#pragma unroll
    for (int nt = 0; nt < 4; ++nt) acc_o[nt] = z;
    acc_n = z;
  }
  bf16x8 ones;
#pragma unroll
  for (int z = 0; z < 8; ++z) ones[z] = (short)0x3F80;

  for (int jt = 0; jt <= it; ++jt) {
    const int cur = jt & 1;
    if (jt < it) stage_kv(cur ^ 1, jt + 1);
    const char* skb = sk[cur];
    const char* svb = sv[cur];
    const int j0 = jt * 64;

    floatx4 s_acc[4];
    {
      floatx4 z = {0.f, 0.f, 0.f, 0.f};
#pragma unroll
      for (int nt = 0; nt < 4; ++nt) s_acc[nt] = z;
    }
#pragma unroll
    for (int ks = 0; ks < 2; ++ks)
#pragma unroll
      for (int nt = 0; nt < 4; ++nt) {
        const bf16x8 bk =
            *(const bf16x8*)(skb + swz(nt * 16 + ln, ks * 64 + qd * 16));
        s_acc[nt] =
            __builtin_amdgcn_mfma_f32_16x16x32_bf16(aq[ks], bk, s_acc[nt], 0, 0, 0);
      }

    float cj[4], sj[4];
#pragma unroll
    for (int nt = 0; nt < 4; ++nt)
      __sincosf(PH * (float)(j0 + nt * 16 + ln), &sj[nt], &cj[nt]);
    const bool diag = (jt == it);
    const int li = w * 16 + qd * 4;
#pragma unroll
    for (int nt = 0; nt < 4; ++nt) {
      const int jl = nt * 16 + ln;
#pragma unroll
      for (int r = 0; r < 4; ++r) {
        float val = s_acc[nt][r] * (ci[r] * cj[nt] + si[r] * sj[nt]);
        if (diag && jl > li + r) val = 0.f;
        *(unsigned short*)(ss + swz(li + r, jl * 2)) = f2bf(val);
      }
    }

#pragma unroll
    for (int ks = 0; ks < 2; ++ks) {
      const bf16x8 as = *(const bf16x8*)(ss + swz(w * 16 + ln, ks * 64 + qd * 16));
#pragma unroll
      for (int nt = 0; nt < 4; ++nt) {
        const bf16x8 bv =
            *(const bf16x8*)(svb + swz(nt * 16 + ln, ks * 64 + qd * 16));
        acc_o[nt] =
            __builtin_amdgcn_mfma_f32_16x16x32_bf16(as, bv, acc_o[nt], 0, 0, 0);
      }
      acc_n = __builtin_amdgcn_mfma_f32_16x16x32_bf16(as, ones, acc_n, 0, 0, 0);
    }
    __syncthreads();
  }

#pragma unroll
  for (int r = 0; r < 4; ++r) {
    const float inv = 1.0f / (acc_n[r] + 1e-6f);
    unsigned short* op =
        out + (size_t)(b * TB_L + i0 + w * 16 + qd * 4 + r) * TB_E + h * 64;
#pragma unroll
    for (int nt = 0; nt < 4; ++nt) op[nt * 16 + ln] = f2bf(acc_o[nt][r] * inv);
  }
}

extern "C" void kernel_launch(void* const* d_in, const int* in_sizes, int n_in,
                              void* d_out, int out_size, void* d_ws, size_t ws_size,
                              hipStream_t stream) {
  const float* x     = (const float*)d_in[0];
  const float* qkv_w = (const float*)d_in[1];
  const float* qkv_b = (const float*)d_in[2];
  const float* out_w = (const float*)d_in[3];
  const float* out_b = (const float*)d_in[4];
  const float* n1w   = (const float*)d_in[5];
  const float* n2w   = (const float*)d_in[6];
  const float* w1    = (const float*)d_in[7];
  const float* b1    = (const float*)d_in[8];
  const float* w2    = (const float*)d_in[9];
  const float* b2    = (const float*)d_in[10];

  char* wsb = (char*)d_ws;
  unsigned short* qkvb  = (unsigned short*)wsb;              // 2048x3072 bf16
  unsigned short* g     = (unsigned short*)wsb;              // later: 2048x4096 bf16
  unsigned short* vt    = (unsigned short*)(wsb + 12582912); // 32x64x1024 bf16 (4MB)
  unsigned short* xnb   = (unsigned short*)(wsb + 16777216);
  unsigned short* attnb = (unsigned short*)(wsb + 20971520);
  float*          h     = (float*)(wsb + 25165824);
  unsigned short* qkvwt = (unsigned short*)(wsb + 33554432);
  unsigned short* outwt = (unsigned short*)(wsb + 39845888);
  unsigned short* w1t   = (unsigned short*)(wsb + 41943040);
  unsigned short* w2t   = (unsigned short*)(wsb + 50331648);
  float*          Pk    = (float*)(wsb + 67108864);  // 2 x 8.4MB fp32 partials
  float* out = (float*)d_out;
  const int M = 2048;

  transpose_all<<<dim3(3072), 256, 0, stream>>>(qkv_w, out_w, w1, w2,
                                                qkvwt, outwt, w1t, w2t);

  rms_kernel<<<dim3(M), 256, 0, stream>>>(x, n1w, xnb);
  // qkv: relu'd q,k in-place; v also transposed into vt
  gemm_bf16<64, 128, 64, 32, 32, 512, false, true><<<dim3(24, 32), 512, 0, stream>>>(
      xnb, qkvwt, qkv_b, nullptr, nullptr, qkvb, nullptr, vt, 2048, M, 3072, 1024, 1024);
  attn_mfma<<<dim3(32, 16), 256, 0, stream>>>(qkvb, vt, attnb);
  gemm_bf16<64, 64, 64, 32, 32, 256, false, false><<<dim3(16, 32), 256, 0, stream>>>(
      attnb, outwt, out_b, x, h, nullptr, nullptr, nullptr, 0, M, 1024, 1024, 1024);
  rms_kernel<<<dim3(M), 256, 0, stream>>>(h, n2w, xnb);
  gemm_bf16<64, 128, 64, 32, 32, 512, true, false><<<dim3(32, 32), 512, 0, stream>>>(
      xnb, w1t, b1, nullptr, nullptr, g, nullptr, nullptr, 0, M, 4096, 1024, 1024);
  gemm_bf16<64, 128, 64, 32, 32, 512, false, false><<<dim3(8, 32, 2), 512, 0, stream>>>(
      g, w2t, nullptr, nullptr, nullptr, nullptr, Pk, nullptr, 0, M, 1024, 4096, 2048);
  reduce_out<<<dim3(2048), 256, 0, stream>>>(Pk, h, b2, out);
}